// Round 2
// baseline (323.767 us; speedup 1.0000x reference)
//
#include <hip/hip_runtime.h>

#define P 7
#define PP 49            // 7*7 pixels per ROI
#define CMAX 256         // channels
#define G 8              // ROIs per cluster (per block)
#define CSPLIT 16        // channel slices -> CMAX/CSPLIT channels per block
#define CSLICE 16        // channels per block
#define NBINS 256        // 4 levels x 8x8 spatial cells

// d_ws layout in u32 words (bucket/hist/cursor live in LDS of prep_kernel):
//   [2560,4608)  perm (sorted roi indices, capacity 2048)
#define WS_PERM   2560

// 8B vector, 4B-aligned: (x0, x0+1) pair in one load. x0==H-1 edge: lx==0 so
// the extra element (still inside the allocation) has zero weight.
typedef float f2 __attribute__((ext_vector_type(2), aligned(4)));

struct PixParam { int o00, o10; float w00, w01, w10, w11; };

__device__ __forceinline__ int roi_level(float x1, float y1, float x2, float y2) {
    const float area = __fmul_rn(__fsub_rn(y2, y1), __fsub_rn(x2, x1));
    int lvl = (int)rintf(log2f(sqrtf(fmaxf(area, 0.0f)) / 224.0f)) + 4;
    return lvl < 2 ? 2 : (lvl > 5 ? 5 : lvl);
}

// ---- fused prep: hist + scan + scatter, one block, everything in LDS ----
__global__ __launch_bounds__(256) void prep_kernel(
    const float* __restrict__ rois, int n, unsigned* __restrict__ ws)
{
    __shared__ unsigned s_hist[NBINS];
    __shared__ unsigned s_cur[NBINS];
    const int t = threadIdx.x;              // 256 threads
    s_hist[t] = 0u;
    __syncthreads();

    unsigned bloc[8];                       // n <= 2048 (ws perm capacity)
    #pragma unroll
    for (int i = 0; i < 8; ++i) {
        const int r = t + i * 256;
        bloc[i] = 0u;
        if (r < n) {
            const float x1 = rois[r*4+0], y1 = rois[r*4+1];
            const float x2 = rois[r*4+2], y2 = rois[r*4+3];
            const int lvl = roi_level(x1, y1, x2, y2);
            int cx = ((int)(__fmul_rn(__fadd_rn(x1, x2), 0.5f))) >> 7; cx = min(cx, 7);
            int cy = ((int)(__fmul_rn(__fadd_rn(y1, y2), 0.5f))) >> 7; cy = min(cy, 7);
            const unsigned b = (unsigned)(((lvl - 2) << 6) | (cy << 3) | cx);
            bloc[i] = b;
            atomicAdd(&s_hist[b], 1u);
        }
    }
    __syncthreads();

    // Hillis-Steele inclusive scan -> exclusive cursor
    const unsigned h = s_hist[t];
    s_cur[t] = h;
    __syncthreads();
    for (int off = 1; off < NBINS; off <<= 1) {
        const unsigned v = (t >= off) ? s_cur[t - off] : 0u;
        __syncthreads();
        s_cur[t] += v;
        __syncthreads();
    }
    s_cur[t] -= h;                          // exclusive prefix
    __syncthreads();

    #pragma unroll
    for (int i = 0; i < 8; ++i) {
        const int r = t + i * 256;
        if (r < n) {
            const unsigned pos = atomicAdd(&s_cur[bloc[i]], 1u);
            ws[WS_PERM + pos] = (unsigned)r;
        }
    }
}

__global__ __launch_bounds__(256) void roialign_main(
    const float* __restrict__ p2, const float* __restrict__ p3,
    const float* __restrict__ p4, const float* __restrict__ p5,
    const float* __restrict__ rois, const unsigned* __restrict__ ws,
    float* __restrict__ out, int n)
{
    __shared__ PixParam sp[G * PP];
    __shared__ const float* fm_s[G];
    __shared__ int hw_s[G];
    __shared__ int H_s[G];
    __shared__ long long obase_s[G];
    __shared__ float box_s[G][4];

    const int nclust = (n + G - 1) / G;          // 250 for n=2000
    const int nwg = nclust * CSPLIT;             // 4000

    // Bijective chunked XCD swizzle (m204): physical blockIdx -> logical id so
    // each XCD gets a CONTIGUOUS run of sorted clusters (same spatial bucket
    // => overlapping feature lines stay in that XCD's 4MB L2).
    const int pb  = blockIdx.x;
    const int q   = nwg >> 3, rmd = nwg & 7;
    const int xcd = pb & 7,   j   = pb >> 3;
    const int l   = (xcd < rmd ? xcd * (q + 1) : rmd * (q + 1) + (xcd - rmd) * q) + j;

    const int cl = l / CSPLIT;                   // cluster id (cluster-major logical order)
    const int cb = l % CSPLIT;                   // channel slice 0..CSPLIT-1
    const int t  = threadIdx.x;

    // ---- per-ROI setup once (not 49x per pixel): level/log2/base ----
    if (t < G) {
        const int gi = cl * G + t;
        long long ob = -1; const float* fm = p2; int H = 4; int hw = 0;
        float bx1 = 0.f, by1 = 0.f, bx2 = 0.f, by2 = 0.f;
        if (gi < n) {
            const int rr = (int)ws[WS_PERM + gi];
            bx1 = rois[rr*4+0]; by1 = rois[rr*4+1];
            bx2 = rois[rr*4+2]; by2 = rois[rr*4+3];
            const int lvl = roi_level(bx1, by1, bx2, by2);
            H = 1024 >> lvl;
            hw = H * H;
            fm = (lvl == 2) ? p2 : (lvl == 3) ? p3 : (lvl == 4) ? p4 : p5;
            ob = (long long)rr * (CMAX * PP);
        }
        fm_s[t] = fm; hw_s[t] = hw; H_s[t] = H; obase_s[t] = ob;
        box_s[t][0] = bx1; box_s[t][1] = by1; box_s[t][2] = bx2; box_s[t][3] = by2;
    }
    __syncthreads();

    // ---- per-(roi,pixel) params into LDS ----
    for (int idx = t; idx < G * PP; idx += 256) {
        const int g = idx / PP, pix = idx % PP;
        PixParam pp; pp.o00 = 0; pp.o10 = 0;
        pp.w00 = 0.f; pp.w01 = 0.f; pp.w10 = 0.f; pp.w11 = 0.f;
        if (obase_s[g] >= 0) {
            const float x1 = box_s[g][0], y1 = box_s[g][1];
            const float x2 = box_s[g][2], y2 = box_s[g][3];
            const int H = H_s[g];
            const int py = pix / P, px = pix % P;
            const float inv = 1.0f / 1024.0f;               // exact pow2
            const float by1 = __fmul_rn(y1, inv), bx1 = __fmul_rn(x1, inv);
            const float by2 = __fmul_rn(y2, inv), bx2 = __fmul_rn(x2, inv);
            const float Hm1 = (float)(H - 1);
            const float ty = (float)py / 6.0f;
            const float tx = (float)px / 6.0f;
            // match numpy op-for-op (no fma contraction)
            const float vy = __fmul_rn(__fadd_rn(by1, __fmul_rn(ty, __fsub_rn(by2, by1))), Hm1);
            const float vx = __fmul_rn(__fadd_rn(bx1, __fmul_rn(tx, __fsub_rn(bx2, bx1))), Hm1);
            const bool vldy = (vy >= 0.0f) && (vy <= Hm1);
            const bool vldx = (vx >= 0.0f) && (vx <= Hm1);
            const float yc = fminf(fmaxf(vy, 0.0f), Hm1);
            const float xc = fminf(fmaxf(vx, 0.0f), Hm1);
            const int y0 = (int)floorf(yc);
            const int x0 = (int)floorf(xc);
            const int y1i = min(y0 + 1, H - 1);
            const float ly = __fsub_rn(yc, (float)y0);
            const float lx = __fsub_rn(xc, (float)x0);      // == 0 when x0 == H-1
            const float m = (vldy && vldx) ? 1.0f : 0.0f;
            const float wy0 = m * (1.0f - ly), wy1 = m * ly;
            const float wx0 = 1.0f - lx,      wx1 = lx;
            pp.o00 = y0 * H + x0;
            pp.o10 = y1i * H + x0;
            pp.w00 = wy0 * wx0;  pp.w01 = wy0 * wx1;
            pp.w10 = wy1 * wx0;  pp.w11 = wy1 * wx1;
        }
        sp[idx] = pp;
    }
    __syncthreads();

    if (t >= 5 * PP) return;            // 245 active
    const int pix = t % PP;
    const int c0  = t / PP;             // 0..4

    // ---- hoist per-g state into registers ----
    const float* pT[G]; const float* pB[G];
    size_t step[G];
    float w00[G], w01[G], w10[G], w11[G];
    long long ob[G];
    #pragma unroll
    for (int g = 0; g < G; ++g) {
        const PixParam pp = sp[g * PP + pix];
        const int hw = hw_s[g];
        const float* base = fm_s[g] + (size_t)(cb * CSLICE + c0) * hw;
        pT[g] = base + pp.o00;
        pB[g] = base + pp.o10;
        step[g] = (size_t)5 * hw;
        w00[g] = pp.w00; w01[g] = pp.w01; w10[g] = pp.w10; w11[g] = pp.w11;
        ob[g] = obase_s[g];
    }

    // ---- channel loop (16 channels: c_local = c0 + 5k < 16) ----
    #pragma unroll
    for (int k = 0; k < 4; ++k) {
        const int clc = c0 + 5 * k;
        if (clc < CSLICE) {             // false only at k==3 for c0>=1 (exec-masked)
            f2 tp[G], bt[G];
            #pragma unroll
            for (int g = 0; g < G; ++g) {       // issue all 16 loads first
                tp[g] = *(const f2*)pT[g];
                bt[g] = *(const f2*)pB[g];
                pT[g] += step[g]; pB[g] += step[g];
            }
            #pragma unroll
            for (int g = 0; g < G; ++g) {       // then consume
                const float v = tp[g].x * w00[g] + tp[g].y * w01[g]
                              + bt[g].x * w10[g] + bt[g].y * w11[g];
                if (ob[g] >= 0) {
                    // write-once output: nontemporal, keep L2 for feature gathers
                    __builtin_nontemporal_store(
                        v, &out[ob[g] + (long long)(cb * CSLICE + clc) * PP + pix]);
                }
            }
        }
    }
}

extern "C" void kernel_launch(void* const* d_in, const int* in_sizes, int n_in,
                              void* d_out, int out_size, void* d_ws, size_t ws_size,
                              hipStream_t stream) {
    const float* p2   = (const float*)d_in[0];
    const float* p3   = (const float*)d_in[1];
    const float* p4   = (const float*)d_in[2];
    const float* p5   = (const float*)d_in[3];
    const float* rois = (const float*)d_in[4];
    float* out = (float*)d_out;
    unsigned* ws = (unsigned*)d_ws;
    const int n = in_sizes[4] / 4;            // B*R = 2000

    prep_kernel<<<1, 256, 0, stream>>>(rois, n, ws);

    const int nclust = (n + G - 1) / G;       // 250
    roialign_main<<<nclust * CSPLIT, 256, 0, stream>>>(p2, p3, p4, p5, rois, ws, out, n);
}

// Round 3
// 282.725 us; speedup vs baseline: 1.1452x; 1.1452x over previous
//
#include <hip/hip_runtime.h>

#define P 7
#define PP 49            // 7*7 pixels per ROI
#define CMAX 256         // channels
#define G 8              // ROIs per cluster (per block)
#define CSPLIT 8         // channel slices -> CMAX/CSPLIT channels per block
#define CSLICE 32        // channels per block
#define NBINS 256        // 4 levels x 8x8 spatial cells
#define CHUNK 8          // clusters per XCD-chunk (balance grain)

// d_ws layout in u32 words (bucket/hist/cursor live in LDS of prep_kernel):
//   [2560,4608)  perm (sorted roi indices, capacity 2048)
#define WS_PERM   2560

// 8B vector, 4B-aligned: (x0, x0+1) pair in one load. x0==H-1 edge: lx==0 so
// the extra element (still inside the allocation) has zero weight.
typedef float f2 __attribute__((ext_vector_type(2), aligned(4)));

struct PixParam { int o00, o10; float w00, w01, w10, w11; };

__device__ __forceinline__ int roi_level(float x1, float y1, float x2, float y2) {
    const float area = __fmul_rn(__fsub_rn(y2, y1), __fsub_rn(x2, x1));
    int lvl = (int)rintf(log2f(sqrtf(fmaxf(area, 0.0f)) / 224.0f)) + 4;
    return lvl < 2 ? 2 : (lvl > 5 ? 5 : lvl);
}

// ---- fused prep: hist + scan + scatter, one block, everything in LDS ----
__global__ __launch_bounds__(256) void prep_kernel(
    const float* __restrict__ rois, int n, unsigned* __restrict__ ws)
{
    __shared__ unsigned s_hist[NBINS];
    __shared__ unsigned s_cur[NBINS];
    const int t = threadIdx.x;              // 256 threads
    s_hist[t] = 0u;
    __syncthreads();

    unsigned bloc[8];                       // n <= 2048 (ws perm capacity)
    #pragma unroll
    for (int i = 0; i < 8; ++i) {
        const int r = t + i * 256;
        bloc[i] = 0u;
        if (r < n) {
            const float x1 = rois[r*4+0], y1 = rois[r*4+1];
            const float x2 = rois[r*4+2], y2 = rois[r*4+3];
            const int lvl = roi_level(x1, y1, x2, y2);
            int cx = ((int)(__fmul_rn(__fadd_rn(x1, x2), 0.5f))) >> 7; cx = min(cx, 7);
            int cy = ((int)(__fmul_rn(__fadd_rn(y1, y2), 0.5f))) >> 7; cy = min(cy, 7);
            const unsigned b = (unsigned)(((lvl - 2) << 6) | (cy << 3) | cx);
            bloc[i] = b;
            atomicAdd(&s_hist[b], 1u);
        }
    }
    __syncthreads();

    // Hillis-Steele inclusive scan -> exclusive cursor
    const unsigned h = s_hist[t];
    s_cur[t] = h;
    __syncthreads();
    for (int off = 1; off < NBINS; off <<= 1) {
        const unsigned v = (t >= off) ? s_cur[t - off] : 0u;
        __syncthreads();
        s_cur[t] += v;
        __syncthreads();
    }
    s_cur[t] -= h;                          // exclusive prefix
    __syncthreads();

    #pragma unroll
    for (int i = 0; i < 8; ++i) {
        const int r = t + i * 256;
        if (r < n) {
            const unsigned pos = atomicAdd(&s_cur[bloc[i]], 1u);
            ws[WS_PERM + pos] = (unsigned)r;
        }
    }
}

__global__ __launch_bounds__(256) void roialign_main(
    const float* __restrict__ p2, const float* __restrict__ p3,
    const float* __restrict__ p4, const float* __restrict__ p5,
    const float* __restrict__ rois, const unsigned* __restrict__ ws,
    float* __restrict__ out, int n)
{
    __shared__ PixParam sp[G * PP];
    __shared__ const float* fm_s[G];
    __shared__ int hw_s[G];
    __shared__ int H_s[G];
    __shared__ long long obase_s[G];
    __shared__ float box_s[G][4];

    const int nclust = (n + G - 1) / G;          // 250 for n=2000

    // Balanced XCD chunking: HW round-robins blockIdx%8 across XCDs. We give
    // each XCD small chunks of CHUNK=8 CONSECUTIVE sorted clusters (spatial
    // neighbors -> overlapping feature lines stay in that XCD's L2), and deal
    // chunks round-robin (chunk c -> XCD c%8) so each level's cluster range is
    // spread evenly over all XCDs (fixes round-2's level imbalance).
    //   b: xcd=b&7, j=b>>3; blocks_per_chunk = CHUNK*CSPLIT = 64
    //   chunk = (j/64)*8 + xcd; within = j&63; cl = chunk*8 + (within&7); cb = within>>3
    const int pb  = blockIdx.x;
    const int xcd = pb & 7, j = pb >> 3;
    const int chunk = (j >> 6) * 8 + xcd;
    const int within = j & 63;
    const int cl = chunk * CHUNK + (within & 7);  // cluster id
    const int cb = within >> 3;                   // channel slice 0..CSPLIT-1
    if (cl >= nclust) return;                     // padded tail chunk (whole block)
    const int t  = threadIdx.x;

    // ---- per-ROI setup once (not 49x per pixel): level/log2/base ----
    if (t < G) {
        const int gi = cl * G + t;
        long long ob = -1; const float* fm = p2; int H = 4; int hw = 0;
        float bx1 = 0.f, by1 = 0.f, bx2 = 0.f, by2 = 0.f;
        if (gi < n) {
            const int rr = (int)ws[WS_PERM + gi];
            bx1 = rois[rr*4+0]; by1 = rois[rr*4+1];
            bx2 = rois[rr*4+2]; by2 = rois[rr*4+3];
            const int lvl = roi_level(bx1, by1, bx2, by2);
            H = 1024 >> lvl;
            hw = H * H;
            fm = (lvl == 2) ? p2 : (lvl == 3) ? p3 : (lvl == 4) ? p4 : p5;
            ob = (long long)rr * (CMAX * PP);
        }
        fm_s[t] = fm; hw_s[t] = hw; H_s[t] = H; obase_s[t] = ob;
        box_s[t][0] = bx1; box_s[t][1] = by1; box_s[t][2] = bx2; box_s[t][3] = by2;
    }
    __syncthreads();

    // ---- per-(roi,pixel) params into LDS ----
    for (int idx = t; idx < G * PP; idx += 256) {
        const int g = idx / PP, pix = idx % PP;
        PixParam pp; pp.o00 = 0; pp.o10 = 0;
        pp.w00 = 0.f; pp.w01 = 0.f; pp.w10 = 0.f; pp.w11 = 0.f;
        if (obase_s[g] >= 0) {
            const float x1 = box_s[g][0], y1 = box_s[g][1];
            const float x2 = box_s[g][2], y2 = box_s[g][3];
            const int H = H_s[g];
            const int py = pix / P, px = pix % P;
            const float inv = 1.0f / 1024.0f;               // exact pow2
            const float by1 = __fmul_rn(y1, inv), bx1 = __fmul_rn(x1, inv);
            const float by2 = __fmul_rn(y2, inv), bx2 = __fmul_rn(x2, inv);
            const float Hm1 = (float)(H - 1);
            const float ty = (float)py / 6.0f;
            const float tx = (float)px / 6.0f;
            // match numpy op-for-op (no fma contraction)
            const float vy = __fmul_rn(__fadd_rn(by1, __fmul_rn(ty, __fsub_rn(by2, by1))), Hm1);
            const float vx = __fmul_rn(__fadd_rn(bx1, __fmul_rn(tx, __fsub_rn(bx2, bx1))), Hm1);
            const bool vldy = (vy >= 0.0f) && (vy <= Hm1);
            const bool vldx = (vx >= 0.0f) && (vx <= Hm1);
            const float yc = fminf(fmaxf(vy, 0.0f), Hm1);
            const float xc = fminf(fmaxf(vx, 0.0f), Hm1);
            const int y0 = (int)floorf(yc);
            const int x0 = (int)floorf(xc);
            const int y1i = min(y0 + 1, H - 1);
            const float ly = __fsub_rn(yc, (float)y0);
            const float lx = __fsub_rn(xc, (float)x0);      // == 0 when x0 == H-1
            const float m = (vldy && vldx) ? 1.0f : 0.0f;
            const float wy0 = m * (1.0f - ly), wy1 = m * ly;
            const float wx0 = 1.0f - lx,      wx1 = lx;
            pp.o00 = y0 * H + x0;
            pp.o10 = y1i * H + x0;
            pp.w00 = wy0 * wx0;  pp.w01 = wy0 * wx1;
            pp.w10 = wy1 * wx0;  pp.w11 = wy1 * wx1;
        }
        sp[idx] = pp;
    }
    __syncthreads();

    if (t >= 5 * PP) return;            // 245 active
    const int pix = t % PP;
    const int c0  = t / PP;             // 0..4

    // ---- hoist per-g state into registers ----
    const float* pT[G]; const float* pB[G];
    size_t step[G];
    float w00[G], w01[G], w10[G], w11[G];
    long long ob[G];
    #pragma unroll
    for (int g = 0; g < G; ++g) {
        const PixParam pp = sp[g * PP + pix];
        const int hw = hw_s[g];
        const float* base = fm_s[g] + (size_t)(cb * CSLICE + c0) * hw;
        pT[g] = base + pp.o00;
        pB[g] = base + pp.o10;
        step[g] = (size_t)5 * hw;
        w00[g] = pp.w00; w01[g] = pp.w01; w10[g] = pp.w10; w11[g] = pp.w11;
        ob[g] = obase_s[g];
    }

    // ---- channel loop (32 channels: c_local = c0 + 5k < 32) ----
    #pragma unroll
    for (int k = 0; k < 7; ++k) {
        const int clc = c0 + 5 * k;
        if (clc < CSLICE) {             // false only at k==6 for c0>=2 (exec-masked)
            f2 tp[G], bt[G];
            #pragma unroll
            for (int g = 0; g < G; ++g) {       // issue all 16 loads first
                tp[g] = *(const f2*)pT[g];
                bt[g] = *(const f2*)pB[g];
                pT[g] += step[g]; pB[g] += step[g];
            }
            #pragma unroll
            for (int g = 0; g < G; ++g) {       // then consume
                const float v = tp[g].x * w00[g] + tp[g].y * w01[g]
                              + bt[g].x * w10[g] + bt[g].y * w11[g];
                if (ob[g] >= 0) {
                    out[ob[g] + (long long)(cb * CSLICE + clc) * PP + pix] = v;
                }
            }
        }
    }
}

extern "C" void kernel_launch(void* const* d_in, const int* in_sizes, int n_in,
                              void* d_out, int out_size, void* d_ws, size_t ws_size,
                              hipStream_t stream) {
    const float* p2   = (const float*)d_in[0];
    const float* p3   = (const float*)d_in[1];
    const float* p4   = (const float*)d_in[2];
    const float* p5   = (const float*)d_in[3];
    const float* rois = (const float*)d_in[4];
    float* out = (float*)d_out;
    unsigned* ws = (unsigned*)d_ws;
    const int n = in_sizes[4] / 4;            // B*R = 2000

    prep_kernel<<<1, 256, 0, stream>>>(rois, n, ws);

    // Blocks: chunks of CHUNK clusters x CSPLIT slices, chunk count padded to
    // a multiple of 8 so the chunk->XCD deal is complete. n=2000 -> 2048 blocks
    // (48 idle tail blocks exit immediately).
    const int nclust  = (n + G - 1) / G;              // 250
    const int nchunk  = (nclust + CHUNK - 1) / CHUNK; // 32
    const int nchunk8 = (nchunk + 7) & ~7;            // 32
    const int nblocks = nchunk8 * CHUNK * CSPLIT;     // 2048
    roialign_main<<<nblocks, 256, 0, stream>>>(p2, p3, p4, p5, rois, ws, out, n);
}